// Round 6
// baseline (471.213 us; speedup 1.0000x reference)
//
#include <hip/hip_runtime.h>
#include <stdint.h>

#define SEQ 4096
#define DIM 1024

typedef __bf16 bf16x8 __attribute__((ext_vector_type(8)));
typedef float f32x4 __attribute__((ext_vector_type(4)));
typedef unsigned short u16;

__device__ __forceinline__ u16 f2bf(float f) {
    unsigned u = __float_as_uint(f);
    u += 0x7fffu + ((u >> 16) & 1u);     // RNE
    return (u16)(u >> 16);
}
__device__ __forceinline__ float bf2f(u16 h) {
    return __uint_as_float(((unsigned)h) << 16);
}

// global(16B) -> LDS direct copy; LDS dest is wave-uniform base + lane*16.
__device__ __forceinline__ void gload16(const u16* g, u16* l) {
    __builtin_amdgcn_global_load_lds(
        (const __attribute__((address_space(1))) void*)g,
        (__attribute__((address_space(3))) void*)l, 16, 0, 0);
}

// ---------------------------------------------------------------------------
// Kernel 1: h = rmsnorm(emb[x]) * norm_w, written as COMBINED hi|lo bf16
// hhl[4096][2048]: cols 0-1023 = hi, 1024-2047 = lo.
// ---------------------------------------------------------------------------
__global__ __launch_bounds__(256) void embed_rmsnorm_split(
    const int* __restrict__ x, const float* __restrict__ emb,
    const float* __restrict__ nw, u16* __restrict__ hhl)
{
    const int row  = blockIdx.x;
    const int t    = threadIdx.x;
    const int lane = t & 63, wave = t >> 6;

    bool i64 = true;
    #pragma unroll
    for (int i = 1; i < 128; i += 2) i64 = i64 && (x[i] == 0);
    const int id = i64 ? x[2 * row] : x[row];

    float4 e = *(const float4*)(emb + (size_t)id * DIM + t * 4);
    float ss = e.x*e.x + e.y*e.y + e.z*e.z + e.w*e.w;
    #pragma unroll
    for (int off = 32; off > 0; off >>= 1) ss += __shfl_down(ss, off);

    __shared__ float red[4];
    if (lane == 0) red[wave] = ss;
    __syncthreads();
    float sum = red[0] + red[1] + red[2] + red[3];
    float scale = rsqrtf(sum * (1.0f / DIM) + 1.1920929e-7f);  // fp32 eps

    float4 n = *(const float4*)(nw + t * 4);
    float o0 = e.x * scale * n.x;
    float o1 = e.y * scale * n.y;
    float o2 = e.z * scale * n.z;
    float o3 = e.w * scale * n.w;
    ushort4 oh, ol;
    u16 b;
    b = f2bf(o0); oh.x = b; ol.x = f2bf(o0 - bf2f(b));
    b = f2bf(o1); oh.y = b; ol.y = f2bf(o1 - bf2f(b));
    b = f2bf(o2); oh.z = b; ol.z = f2bf(o2 - bf2f(b));
    b = f2bf(o3); oh.w = b; ol.w = f2bf(o3 - bf2f(b));
    *(ushort4*)(hhl + (size_t)row * 2048 + t * 4)        = oh;
    *(ushort4*)(hhl + (size_t)row * 2048 + t * 4 + 1024) = ol;
}

// ---------------------------------------------------------------------------
// Kernel 1b: split Wq/Wk/Wv fp32 -> COMBINED hi|lo bf16 Whl[3072][2048]
// ---------------------------------------------------------------------------
__global__ __launch_bounds__(256) void split_w(
    const float* __restrict__ W0, const float* __restrict__ W1,
    const float* __restrict__ W2, u16* __restrict__ Whl)
{
    const float* W = (blockIdx.y == 0) ? W0 : (blockIdx.y == 1) ? W1 : W2;
    const int i   = (blockIdx.x * 256 + threadIdx.x) * 4;
    const int row = i >> 10;
    const int col = i & 1023;
    float4 w = *(const float4*)(W + i);
    ushort4 h, l;
    u16 b;
    b = f2bf(w.x); h.x = b; l.x = f2bf(w.x - bf2f(b));
    b = f2bf(w.y); h.y = b; l.y = f2bf(w.y - bf2f(b));
    b = f2bf(w.z); h.z = b; l.z = f2bf(w.z - bf2f(b));
    b = f2bf(w.w); h.w = b; l.w = f2bf(w.w - bf2f(b));
    u16* d = Whl + (size_t)(blockIdx.y * 1024 + row) * 2048 + col;
    *(ushort4*)(d)        = h;
    *(ushort4*)(d + 1024) = l;
}

// ---------------------------------------------------------------------------
// Kernel 2: TRUE-K split-precision 256xBN 8-phase GEMM, BK=32, K=1024.
// BN = NF*64 (NF=4 -> 256, NF=3 -> 192). NF=3 exists so the QKV GEMM
// (N=3072) gets a 256-block grid = 100% machine fill (R5: 12x16=192 blocks
// = 75% fill was the whole QKV deficit; per-CU rate already matched Sc).
//
// acc += Ah.Bh + Ah.Bl + Al.Bh per 32-K tile (R1-proven order).
// LDS: A 64 KB + B NF*16 KB (dbuf, both hi+lo). 8 waves (2M x 4N),
// per-wave 128 x NF*16.
//
// Swizzle (R5-verified, 0 bank conflicts): LDS[row][c] = G[row][c ^
// 8*((row>>1)&3)]; write side scol = 8*((tid&3)^((tid>>3)&3)); read side
// rc = 8*(half ^ ((l16>>1)&3)).
//
// Phase plan (tile t, buffer b=t&1, staging t+2 into b):
//  p0: read A mf0-3 + B nf0-1;            MFMA mf0-3 x nf0-1
//  p1: read B nf2..NF-1;                  MFMA mf0-3 x nf2..
//  p2: read A mf4-7; stage B(t+2);        MFMA mf4-7 x nf2..
//  p3: stage A(t+2);                      MFMA mf4-7 x nf0-1; vmcnt; barrier
// Steady vmcnt = per-wave loads/tile: NF=4: 8 all waves; NF=3: B's 64-row
// tail unit is staged by waves 4-7 only -> waves 0-3: 6, waves 4-7: 8.
// EPI=0: C fp32 [SEQ,SEQ].  EPI=1: QKV split-write qhl/khl + vT transposed
// (region q/k/v computed PER FRAGMENT: a 192-wide tile can span regions).
// ---------------------------------------------------------------------------
#define NT32 32
template<int EPI, int NF>
__global__ __launch_bounds__(512, 2) void gemm_bk32(
    const u16* __restrict__ A, const u16* __restrict__ B,
    float* __restrict__ C,
    u16* __restrict__ O0, u16* __restrict__ O1, u16* __restrict__ OT)
{
    constexpr int BN = NF * 64;
    __shared__ __align__(16) u16 AhL[2][8192];
    __shared__ __align__(16) u16 AlL[2][8192];
    __shared__ __align__(16) u16 BhL[2][NF * 2048];
    __shared__ __align__(16) u16 BlL[2][NF * 2048];

    const int tid  = threadIdx.x;
    const int lane = tid & 63;
    const int wid  = tid >> 6;
    const int wm   = wid >> 2;      // 0..1
    const int wn   = wid & 3;       // 0..3
    const int l16  = lane & 15;
    const int half = lane >> 4;     // 0..3

    // XCD-aware bijective swizzle (nwg = 256, 256 % 8 == 0)
    const int nx  = gridDim.x;
    const int nwg = nx * gridDim.y;
    const int wg  = blockIdx.y * nx + blockIdx.x;
    const int swz = (wg & 7) * (nwg >> 3) + (wg >> 3);
    const int m0  = (swz / nx) * 256;
    const int n0  = (swz % nx) * BN;

    // staging: thread t -> row t>>2, source col pre-permuted (see header)
    const int srow = tid >> 2;
    const int scol = ((tid & 3) ^ ((tid >> 3) & 3)) * 8;
    const int ldst = tid * 8;                      // u16 offset within unit
    const u16* pAh0 = A + (size_t)(m0 + srow) * 2048 + scol;
    const u16* pAh1 = A + (size_t)(m0 + 128 + srow) * 2048 + scol;
    const u16* pAl0 = pAh0 + 1024;
    const u16* pAl1 = pAh1 + 1024;
    const u16* pBh0 = B + (size_t)(n0 + srow) * 2048 + scol;
    const u16* pBl0 = pBh0 + 1024;
    // B tail unit: NF=4: rows 128-255 by all threads (dest 4096+ldst);
    //              NF=3: rows 128-191 by waves 4-7 only (dest 2048+ldst,
    //              tid in [256,512) -> srow in [64,128) -> row n0+64+srow).
    const u16* pBh1 = (NF == 4) ? B + (size_t)(n0 + 128 + srow) * 2048 + scol
                                : B + (size_t)(n0 +  64 + srow) * 2048 + scol;
    const u16* pBl1 = pBh1 + 1024;
    const int  bdst1 = (NF == 4) ? 4096 + ldst : 2048 + ldst;
    const bool doB1  = (NF == 4) || (wid >= 4);

    // -------- prologue: stage tile0 -> buf0 (k=0), tile1 -> buf1 (k=32)
    #pragma unroll
    for (int kk = 0; kk < 2; ++kk) {
        gload16(pAh0 + kk * 32, &AhL[kk][ldst]);
        gload16(pAh1 + kk * 32, &AhL[kk][4096 + ldst]);
        gload16(pAl0 + kk * 32, &AlL[kk][ldst]);
        gload16(pAl1 + kk * 32, &AlL[kk][4096 + ldst]);
        gload16(pBh0 + kk * 32, &BhL[kk][ldst]);
        gload16(pBl0 + kk * 32, &BlL[kk][ldst]);
        if (doB1) {
            gload16(pBh1 + kk * 32, &BhL[kk][bdst1]);
            gload16(pBl1 + kk * 32, &BlL[kk][bdst1]);
        }
    }
    if (NF == 4 || wid >= 4) { asm volatile("s_waitcnt vmcnt(8)" ::: "memory"); }
    else                     { asm volatile("s_waitcnt vmcnt(6)" ::: "memory"); }
    __builtin_amdgcn_sched_barrier(0);
    __builtin_amdgcn_s_barrier();

    f32x4 acc[8][NF] = {};
    // read addressing (swizzled, 0-conflict measured R5)
    const int rc = 8 * (half ^ ((l16 >> 1) & 3));
    const int ab = (wm * 128 + l16) * 32 + rc;        // + mf*512
    const int bb = (wn * (NF * 16) + l16) * 32 + rc;  // + nf*512

    bf16x8 ah[4], al[4], bh[NF], bl[NF];

    #pragma unroll 1
    for (int t = 0; t < NT32; ++t) {
        const int  b  = t & 1;
        const bool ds = (t + 2) < NT32;
        const int  k2 = (t + 2) * 32;

        // ---- phase 0
        #pragma unroll
        for (int i = 0; i < 4; ++i) {
            ah[i] = *(const bf16x8*)&AhL[b][ab + i * 512];
            al[i] = *(const bf16x8*)&AlL[b][ab + i * 512];
        }
        #pragma unroll
        for (int g = 0; g < 2; ++g) {
            bh[g] = *(const bf16x8*)&BhL[b][bb + g * 512];
            bl[g] = *(const bf16x8*)&BlL[b][bb + g * 512];
        }
        __builtin_amdgcn_s_barrier();
        asm volatile("s_waitcnt lgkmcnt(0)" ::: "memory");
        __builtin_amdgcn_sched_barrier(0);
        __builtin_amdgcn_s_setprio(1);
        #pragma unroll
        for (int i = 0; i < 4; ++i)
            #pragma unroll
            for (int g = 0; g < 2; ++g) {
                acc[i][g] = __builtin_amdgcn_mfma_f32_16x16x32_bf16(ah[i], bh[g], acc[i][g], 0, 0, 0);
                acc[i][g] = __builtin_amdgcn_mfma_f32_16x16x32_bf16(ah[i], bl[g], acc[i][g], 0, 0, 0);
                acc[i][g] = __builtin_amdgcn_mfma_f32_16x16x32_bf16(al[i], bh[g], acc[i][g], 0, 0, 0);
            }
        __builtin_amdgcn_s_setprio(0);
        __builtin_amdgcn_s_barrier();

        // ---- phase 1
        #pragma unroll
        for (int g = 2; g < NF; ++g) {
            bh[g] = *(const bf16x8*)&BhL[b][bb + g * 512];
            bl[g] = *(const bf16x8*)&BlL[b][bb + g * 512];
        }
        __builtin_amdgcn_s_barrier();
        asm volatile("s_waitcnt lgkmcnt(0)" ::: "memory");
        __builtin_amdgcn_sched_barrier(0);
        __builtin_amdgcn_s_setprio(1);
        #pragma unroll
        for (int i = 0; i < 4; ++i)
            #pragma unroll
            for (int g = 2; g < NF; ++g) {
                acc[i][g] = __builtin_amdgcn_mfma_f32_16x16x32_bf16(ah[i], bh[g], acc[i][g], 0, 0, 0);
                acc[i][g] = __builtin_amdgcn_mfma_f32_16x16x32_bf16(ah[i], bl[g], acc[i][g], 0, 0, 0);
                acc[i][g] = __builtin_amdgcn_mfma_f32_16x16x32_bf16(al[i], bh[g], acc[i][g], 0, 0, 0);
            }
        __builtin_amdgcn_s_setprio(0);
        __builtin_amdgcn_s_barrier();

        // ---- phase 2 (B fully read after p1-end barrier -> stage B here)
        #pragma unroll
        for (int i = 0; i < 4; ++i) {
            ah[i] = *(const bf16x8*)&AhL[b][ab + 2048 + i * 512];
            al[i] = *(const bf16x8*)&AlL[b][ab + 2048 + i * 512];
        }
        if (ds) {
            gload16(pBh0 + k2, &BhL[b][ldst]);
            gload16(pBl0 + k2, &BlL[b][ldst]);
            if (doB1) {
                gload16(pBh1 + k2, &BhL[b][bdst1]);
                gload16(pBl1 + k2, &BlL[b][bdst1]);
            }
        }
        __builtin_amdgcn_s_barrier();
        asm volatile("s_waitcnt lgkmcnt(0)" ::: "memory");
        __builtin_amdgcn_sched_barrier(0);
        __builtin_amdgcn_s_setprio(1);
        #pragma unroll
        for (int i = 0; i < 4; ++i)
            #pragma unroll
            for (int g = 2; g < NF; ++g) {
                acc[4 + i][g] = __builtin_amdgcn_mfma_f32_16x16x32_bf16(ah[i], bh[g], acc[4 + i][g], 0, 0, 0);
                acc[4 + i][g] = __builtin_amdgcn_mfma_f32_16x16x32_bf16(ah[i], bl[g], acc[4 + i][g], 0, 0, 0);
                acc[4 + i][g] = __builtin_amdgcn_mfma_f32_16x16x32_bf16(al[i], bh[g], acc[4 + i][g], 0, 0, 0);
            }
        __builtin_amdgcn_s_setprio(0);
        __builtin_amdgcn_s_barrier();

        // ---- phase 3 (A fully read after p2-end barrier -> stage A here)
        if (ds) {
            gload16(pAh0 + k2, &AhL[b][ldst]);
            gload16(pAh1 + k2, &AhL[b][4096 + ldst]);
            gload16(pAl0 + k2, &AlL[b][ldst]);
            gload16(pAl1 + k2, &AlL[b][4096 + ldst]);
        }
        __builtin_amdgcn_s_barrier();
        __builtin_amdgcn_s_setprio(1);
        #pragma unroll
        for (int i = 0; i < 4; ++i)
            #pragma unroll
            for (int g = 0; g < 2; ++g) {
                acc[4 + i][g] = __builtin_amdgcn_mfma_f32_16x16x32_bf16(ah[i], bh[g], acc[4 + i][g], 0, 0, 0);
                acc[4 + i][g] = __builtin_amdgcn_mfma_f32_16x16x32_bf16(ah[i], bl[g], acc[4 + i][g], 0, 0, 0);
                acc[4 + i][g] = __builtin_amdgcn_mfma_f32_16x16x32_bf16(al[i], bh[g], acc[4 + i][g], 0, 0, 0);
            }
        __builtin_amdgcn_s_setprio(0);
        if (t < NT32 - 2) {
            if (NF == 4 || wid >= 4) { asm volatile("s_waitcnt vmcnt(8)" ::: "memory"); }
            else                     { asm volatile("s_waitcnt vmcnt(6)" ::: "memory"); }
        } else {
            asm volatile("s_waitcnt vmcnt(0)" ::: "memory");
        }
        __builtin_amdgcn_sched_barrier(0);
        __builtin_amdgcn_s_barrier();
    }

    // epilogue: C/D layout col=lane&15, row=(lane>>4)*4+reg
    const int crow0 = m0 + wm * 128 + half * 4;
    const int wcol  = n0 + wn * (NF * 16);
    if constexpr (EPI == 0) {
        #pragma unroll
        for (int mf = 0; mf < 8; ++mf)
            #pragma unroll
            for (int nf = 0; nf < NF; ++nf)
                #pragma unroll
                for (int r = 0; r < 4; ++r)
                    C[(size_t)(crow0 + mf * 16 + r) * SEQ + wcol + nf * 16 + l16] = acc[mf][nf][r];
    } else {
        #pragma unroll
        for (int nf = 0; nf < NF; ++nf) {
            const int base = wcol + nf * 16;       // fragment base col
            const int reg  = base >> 10;           // 0=q,1=k,2=v (frag-uniform)
            const int c    = (base & 1023) + l16;
            #pragma unroll
            for (int mf = 0; mf < 8; ++mf)
                #pragma unroll
                for (int r = 0; r < 4; ++r) {
                    const int row = crow0 + mf * 16 + r;
                    const float val = acc[mf][nf][r];
                    const u16 hi = f2bf(val);
                    if (reg == 0) {
                        O0[(size_t)row * 2048 + c]        = hi;
                        O0[(size_t)row * 2048 + c + 1024] = f2bf(val - bf2f(hi));
                    } else if (reg == 1) {
                        O1[(size_t)row * 2048 + c]        = hi;
                        O1[(size_t)row * 2048 + c + 1024] = f2bf(val - bf2f(hi));
                    } else {
                        OT[(size_t)c * SEQ + row] = hi;
                    }
                }
        }
    }
}

// ---------------------------------------------------------------------------
// Kernel 4: row softmax over fp32 [SEQ, SEQ]; writes bf16 P packed in-place
// (float cols [2048,4096) of each row become DEAD -> reused as PV partials)
// ---------------------------------------------------------------------------
__global__ __launch_bounds__(256) void softmax_rows(float* __restrict__ S)
{
    const int row  = blockIdx.x;
    const int t    = threadIdx.x;
    const int lane = t & 63, wave = t >> 6;
    float* rp = S + (size_t)row * SEQ;

    float v[16];
    #pragma unroll
    for (int i = 0; i < 4; ++i) {
        float4 f = *(const float4*)(rp + i * 1024 + t * 4);
        v[i*4+0] = f.x; v[i*4+1] = f.y; v[i*4+2] = f.z; v[i*4+3] = f.w;
    }

    float m = v[0];
    #pragma unroll
    for (int i = 1; i < 16; ++i) m = fmaxf(m, v[i]);
    #pragma unroll
    for (int off = 32; off > 0; off >>= 1) m = fmaxf(m, __shfl_down(m, off));
    __shared__ float red[4];
    if (lane == 0) red[wave] = m;
    __syncthreads();
    m = fmaxf(fmaxf(red[0], red[1]), fmaxf(red[2], red[3]));
    __syncthreads();

    float s = 0.0f;
    #pragma unroll
    for (int i = 0; i < 16; ++i) { v[i] = __expf(v[i] - m); s += v[i]; }
    #pragma unroll
    for (int off = 32; off > 0; off >>= 1) s += __shfl_down(s, off);
    if (lane == 0) red[wave] = s;
    __syncthreads();
    s = red[0] + red[1] + red[2] + red[3];
    float inv = 1.0f / s;

    u16* op = (u16*)rp;
    #pragma unroll
    for (int i = 0; i < 4; ++i) {
        ushort4 o;
        o.x = f2bf(v[i*4+0] * inv);
        o.y = f2bf(v[i*4+1] * inv);
        o.z = f2bf(v[i*4+2] * inv);
        o.w = f2bf(v[i*4+3] * inv);
        *(ushort4*)(op + i * 1024 + t * 4) = o;
    }
}

// ---------------------------------------------------------------------------
// Kernel 5: PV GEMM, split-K=4 (1024 blocks -> 4 blocks/CU: the 128x128
// 2-phase structure's proven ~900 TF regime; 2/CU was ~30% slower).
// Partials: z=0 -> P0, z=1 -> P1, z=2,3 -> the dead float cols [2048,4096)
// of Sc's rows (pitch 4096), disjoint from the P bf16 reads [0,2048).
// ---------------------------------------------------------------------------
__global__ __launch_bounds__(256, 3) void gemm_pv_partial(
    const u16* __restrict__ A, const u16* __restrict__ B,
    float* __restrict__ P0, float* __restrict__ P1, float* __restrict__ Sg)
{
    __shared__ __align__(16) u16 As[128 * 32];
    __shared__ __align__(16) u16 Bs[128 * 32];

    const int tid  = threadIdx.x;
    const int lane = tid & 63;
    const int wave = tid >> 6;
    const int m0   = blockIdx.y * 128;
    const int n0   = blockIdx.x * 128;
    const int wr   = (wave >> 1) * 64;
    const int wc   = (wave & 1) * 64;
    const int half = lane >> 4;
    const int l16  = lane & 15;

    const int z = blockIdx.z;
    float* C;
    int ldc2;
    if      (z == 0) { C = P0;                      ldc2 = 1024; }
    else if (z == 1) { C = P1;                      ldc2 = 1024; }
    else             { C = Sg + 2048 + (z - 2) * 1024; ldc2 = 4096; }
    const int kbase = z * 1024;

    f32x4 acc[4][4] = {};
    const int arow = tid >> 2;
    const int acol = (tid & 3) * 8;
    const int wb   = wave * 512;

    for (int k0 = kbase; k0 < kbase + 1024; k0 += 32) {
        __syncthreads();
        gload16(A + (size_t)(m0 + arow)      * 8192 + k0 + acol, &As[wb]);
        gload16(A + (size_t)(m0 + 64 + arow) * 8192 + k0 + acol, &As[2048 + wb]);
        gload16(B + (size_t)(n0 + arow)      * 4096 + k0 + acol, &Bs[wb]);
        gload16(B + (size_t)(n0 + 64 + arow) * 4096 + k0 + acol, &Bs[2048 + wb]);
        __syncthreads();

        bf16x8 af[4], bfr[4];
        #pragma unroll
        for (int i = 0; i < 4; ++i)
            af[i] = *(const bf16x8*)&As[(wr + i*16 + l16) * 32 + half * 8];
        #pragma unroll
        for (int j = 0; j < 4; ++j)
            bfr[j] = *(const bf16x8*)&Bs[(wc + j*16 + l16) * 32 + half * 8];
        #pragma unroll
        for (int i = 0; i < 4; ++i)
            #pragma unroll
            for (int j = 0; j < 4; ++j)
                acc[i][j] = __builtin_amdgcn_mfma_f32_16x16x32_bf16(af[i], bfr[j], acc[i][j], 0, 0, 0);
    }

    #pragma unroll
    for (int i = 0; i < 4; ++i)
        #pragma unroll
        for (int j = 0; j < 4; ++j)
            #pragma unroll
            for (int r = 0; r < 4; ++r) {
                int row = m0 + wr + i * 16 + half * 4 + r;
                int col = n0 + wc + j * 16 + l16;
                C[(size_t)row * ldc2 + col] = acc[i][j][r];
            }
}

// ---------------------------------------------------------------------------
// Kernel 6: out = silu(P0 + P1 + P2 + P3), P2/P3 in Sc row-gaps
// ---------------------------------------------------------------------------
__global__ __launch_bounds__(256) void combine_silu4(
    const float* __restrict__ P0, const float* __restrict__ P1,
    const float* __restrict__ Sg, float* __restrict__ out)
{
    const int i = (blockIdx.x * 256 + threadIdx.x) * 4;
    const int r = i >> 10;
    const int c = i & 1023;
    const float* g = Sg + (size_t)r * 4096 + 2048 + c;
    float4 a = *(const float4*)(P0 + i);
    float4 b = *(const float4*)(P1 + i);
    float4 d = *(const float4*)(g);
    float4 e = *(const float4*)(g + 1024);
    float4 o;
    float v;
    v = a.x + b.x + d.x + e.x; o.x = v / (1.0f + __expf(-v));
    v = a.y + b.y + d.y + e.y; o.y = v / (1.0f + __expf(-v));
    v = a.z + b.z + d.z + e.z; o.z = v / (1.0f + __expf(-v));
    v = a.w + b.w + d.w + e.w; o.w = v / (1.0f + __expf(-v));
    *(float4*)(out + i) = o;
}

// ---------------------------------------------------------------------------
extern "C" void kernel_launch(void* const* d_in, const int* in_sizes, int n_in,
                              void* d_out, int out_size, void* d_ws, size_t ws_size,
                              hipStream_t stream)
{
    const int*   x   = (const int*)d_in[0];
    const float* emb = (const float*)d_in[1];
    const float* nw  = (const float*)d_in[2];
    const float* Wq  = (const float*)d_in[3];
    const float* Wk  = (const float*)d_in[4];
    const float* Wv  = (const float*)d_in[5];
    float* out = (float*)d_out;

    // ws layout (104 MB total, proven):
    //   [  0,  8) vT   bf16 [DIM,SEQ]             (QKV -> PV)
    //   [  8, 24) qhl  bf16 [SEQ,2048]=[qh|ql]    (QKV -> Sc)
    //   [ 24, 40) khl  bf16 [SEQ,2048]=[kh|kl]    (QKV -> Sc)
    //   [ 40,104) Sc   fp32 [SEQ,SEQ]
    //   hhl[40,56) Whl[56,68) overlap Sc head; dead before Sc GEMM writes.
    //   P0[8,24) P1[24,40) overlap q/k; q/k dead before PV writes.
    //   P2/P3 live in Sc's dead row-halves (float cols [2048,4096)).
    char* ws = (char*)d_ws;
    u16*   vT  = (u16*)(ws);
    u16*   qhl = (u16*)(ws + ( 8u << 20));
    u16*   khl = (u16*)(ws + (24u << 20));
    float* Sc  = (float*)(ws + (40u << 20));
    u16*   hhl = (u16*)(ws + (40u << 20));   // [4096,2048] hi|lo
    u16*   Whl = (u16*)(ws + (56u << 20));   // [3072,2048] hi|lo
    float* P0  = (float*)(ws + ( 8u << 20));
    float* P1  = (float*)(ws + (24u << 20));

    embed_rmsnorm_split<<<SEQ, 256, 0, stream>>>(x, emb, nw, hhl);
    split_w<<<dim3(DIM * DIM / 1024, 3), 256, 0, stream>>>(Wq, Wk, Wv, Whl);

    // fused QKV: [4096,3072] = (hh+hl) x (Wh+Wl)^T, BN=192 -> 16x16=256
    // blocks, 100% fill (BN=256 gave 192 blocks = 75%)
    gemm_bk32<1, 3><<<dim3(3072 / 192, SEQ / 256), 512, 0, stream>>>(
        hhl, Whl, nullptr, qhl, khl, vT);

    // Sc = q.k^T, BN=256, 256 blocks
    gemm_bk32<0, 4><<<dim3(SEQ / 256, SEQ / 256), 512, 0, stream>>>(
        qhl, khl, Sc, nullptr, nullptr, nullptr);

    softmax_rows<<<SEQ, 256, 0, stream>>>(Sc);

    // PV split-K4: P (bf16, pitch 8192) x vT -> 4 partials
    gemm_pv_partial<<<dim3(DIM / 128, SEQ / 128, 4), 256, 0, stream>>>(
        (const u16*)Sc, vT, P0, P1, Sc);

    combine_silu4<<<SEQ * DIM / 1024, 256, 0, stream>>>(P0, P1, Sc, out);
}